// Round 4
// baseline (644.364 us; speedup 1.0000x reference)
//
#include <hip/hip_runtime.h>

#define NEGF -1e30f
#define EPSF 1e-5f

typedef __attribute__((ext_vector_type(8))) short bf16x8;
typedef __attribute__((ext_vector_type(4))) float f32x4;
typedef unsigned short u16;
typedef unsigned int u32;

// ws layout, ushort units
#define WSU_PW 0            // 4 x 128x128 bf16, natural [o][c]
#define WSU_FC 65536        // [o][c]
#define WSU_WO 81920        // [f][j]
#define WSU_WQ 98304        // [j][l]
#define WSU_WK 114688
#define WSU_WV 131072
#define WSU_END 147456      // then PE as float[16384]

__device__ __forceinline__ u16 f2bf(float x) {
  u32 u = __float_as_uint(x);
  u += 0x7fffu + ((u >> 16) & 1u);
  return (u16)(u >> 16);
}
__device__ __forceinline__ float bf2f(u16 u) {
  return __uint_as_float(((u32)u) << 16);
}
__device__ __forceinline__ f32x4 mfma16(bf16x8 a, bf16x8 b, f32x4 c) {
  return __builtin_amdgcn_mfma_f32_16x16x32_bf16(a, b, c, 0, 0, 0);
}
__device__ __forceinline__ void mm_frags(const u16* base, bf16x8* f) {
  f[0] = *(const bf16x8*)(base);
  f[1] = *(const bf16x8*)(base + 32);
  f[2] = *(const bf16x8*)(base + 64);
  f[3] = *(const bf16x8*)(base + 96);
}

__global__ __launch_bounds__(128) void prep_kernel(
    const float* __restrict__ pw_w, const float* __restrict__ fc_w,
    const float* __restrict__ Wo, const float* __restrict__ Wq,
    const float* __restrict__ Wk, const float* __restrict__ Wv,
    u16* __restrict__ wsu) {
  int job = blockIdx.x, r = blockIdx.y, c = threadIdx.x;
  int idx = r * 128 + c;
  if (job < 4)       wsu[WSU_PW + job * 16384 + idx] = f2bf(pw_w[job * 16384 + idx]);
  else if (job == 4) wsu[WSU_FC + idx] = f2bf(fc_w[idx]);
  else if (job == 5) wsu[WSU_WO + idx] = f2bf(Wo[idx]);
  else if (job == 6) wsu[WSU_WQ + idx] = f2bf(Wq[idx]);
  else if (job == 7) wsu[WSU_WK + idx] = f2bf(Wk[idx]);
  else if (job == 8) wsu[WSU_WV + idx] = f2bf(Wv[idx]);
  else {
    float* pe = (float*)(wsu + WSU_END);
    int d = r, pos = c;
    double freq, phase;
    if ((d & 1) == 0) { freq = pow(10000.0, -(double)d / 128.0); phase = 0.0; }
    else { freq = -pow(10000.0, (1.0 - (double)d) / 128.0); phase = 1.5707963267948966; }
    pe[d * 128 + pos] = (float)sin((double)pos * freq + phase);
  }
}

// plane LN stats over 1024 threads x 16 regs
__device__ __forceinline__ void ln_stats(const float* resv, float* red, int t,
                                         float& mu, float& inv) {
  float s = 0.f, s2 = 0.f;
#pragma unroll
  for (int i = 0; i < 16; i++) { float v = resv[i]; s += v; s2 += v * v; }
#pragma unroll
  for (int off = 32; off > 0; off >>= 1) {
    s += __shfl_down(s, off, 64);
    s2 += __shfl_down(s2, off, 64);
  }
  if ((t & 63) == 0) { red[(t >> 6) * 2] = s; red[(t >> 6) * 2 + 1] = s2; }
  __syncthreads();
  float S = 0.f, S2 = 0.f;
#pragma unroll
  for (int i = 0; i < 16; i++) { S += red[2 * i]; S2 += red[2 * i + 1]; }
  mu = S * (1.0f / 16384.0f);
  float var = S2 * (1.0f / 16384.0f) - mu * mu;
  inv = rsqrtf(var + EPSF);
}

// LDS budget: A_raw 34,848 + VTb 8,704 + EX 2,048 + mask 512 + red 128
//           = 46,240 B  (<= 46.5 KiB; 2 blocks = 92.5 KiB under any pool rule)
// Everything else (conv h^T, pointwise/Wo/FC staging, QH/KH, PN, ATT, XT)
// lives INSIDE A via in-place phases (read -> barrier -> write) and the
// register-hoisted MHA X-fragments.
// No min-waves hint: 2-block residency needs VGPR <= 64, which this code is
// written to hit naturally (att packed bf16, sc halved, PV frag-streamed).
__global__ __launch_bounds__(1024) void enc_kernel(
    const float* __restrict__ x, const int* __restrict__ mask,
    const float* __restrict__ dw_w, const float* __restrict__ dw_b,
    const float* __restrict__ pw_b,
    const float* __restrict__ normb_w, const float* __restrict__ normb_b,
    const float* __restrict__ norms_w, const float* __restrict__ norms_b,
    const float* __restrict__ norme_w, const float* __restrict__ norme_b,
    const float* __restrict__ bq, const float* __restrict__ bk,
    const float* __restrict__ bv, const float* __restrict__ bo,
    const float* __restrict__ fc_b, const u16* __restrict__ wsu,
    const float* __restrict__ pe, float* __restrict__ out) {
  __shared__ __align__(16) u16 A_raw[128 * 136 + 16];
  __shared__ __align__(16) u16 VTb[32 * 136];   // V^T for current head
  __shared__ float EX[512];                     // [0,256) row max, [256,512) row sum
  __shared__ float mask_s[128];
  __shared__ float red[32];
  u16* A = A_raw + 8;
  // MHA overlays inside A (Xn is register-hoisted before MHA):
  u16* QH = A;              // 128 x 32, stride 40  (5120)
  u16* KH = A + 5120;       // 128 x 32, stride 40  (5120)
  u16* PN = A;              // 128 x 136 (17408 <= 17415 usable)

  const int t = threadIdx.x;
  const int b = blockIdx.x;
  const int lane = t & 63;
  const int r16 = lane & 15;
  const int quad = lane >> 4;
  const int wv = t >> 6;                                            // 0..15
  const int m0 = __builtin_amdgcn_readfirstlane((wv >> 1) << 4);    // matmul m-tile
  const int nh = __builtin_amdgcn_readfirstlane(wv & 1);            // matmul n-half
  const int l = t & 127;
  const int og = __builtin_amdgcn_readfirstlane(t >> 7);            // 0..7
  const int obase = og << 4;                                        // owned 16 rows
  const int dup = __builtin_amdgcn_readfirstlane(wv >> 3);          // attn key/dim half
  const int mq0 = __builtin_amdgcn_readfirstlane((wv & 7) << 4);    // attn m-tile

  if (t < 128) mask_s[t] = (float)mask[b * 128 + t];

  float res[16];
  {
    const float* xb = x + (size_t)b * 16384;
#pragma unroll
    for (int i = 0; i < 16; i++) {
      int o = obase + i;
      res[i] = xb[o * 128 + l] + pe[o * 128 + l];
    }
  }
  {
    float mu, inv;
    ln_stats(res, red, t, mu, inv);
#pragma unroll
    for (int i = 0; i < 16; i++) {
      int o = obase + i;
      A[o * 136 + l] = f2bf((res[i] - mu) * inv * normb_w[o * 128 + l] + normb_b[o * 128 + l]);
    }
    __syncthreads();
  }

  // ================= 4x separable conv blocks (in-place in A) =================
#pragma unroll 1
  for (int layer = 0; layer < 4; layer++) {
    // depthwise conv7: read own row segment+halo -> regs, barrier, write h^T into A
    {
      const float* dwp = dw_w + layer * 896 + l * 7;
      float wreg[7];
#pragma unroll
      for (int j = 0; j < 7; j++) wreg[j] = dwp[j];
      float bias = dw_b[layer * 128 + l];
      const u16* xrow = A + l * 136;
      const int lb = og << 4;
      bf16x8 vz = {0, 0, 0, 0, 0, 0, 0, 0};
      bf16x8 v0 = (lb == 0) ? vz : *(const bf16x8*)(xrow + lb - 8);
      bf16x8 v1 = *(const bf16x8*)(xrow + lb);
      bf16x8 v2 = *(const bf16x8*)(xrow + lb + 8);
      bf16x8 v3 = (lb == 112) ? vz : *(const bf16x8*)(xrow + lb + 16);
      __syncthreads();  // all Xn reads complete before any h^T write
#pragma unroll
      for (int k = 0; k < 2; k++) {
        bf16x8 vp = k ? v1 : v0;
        bf16x8 vc = k ? v2 : v1;
        bf16x8 vn = k ? v3 : v2;
        float w14[14];
        w14[0] = bf2f((u16)vp[5]); w14[1] = bf2f((u16)vp[6]); w14[2] = bf2f((u16)vp[7]);
#pragma unroll
        for (int j = 0; j < 8; j++) w14[3 + j] = bf2f((u16)vc[j]);
        w14[11] = bf2f((u16)vn[0]); w14[12] = bf2f((u16)vn[1]); w14[13] = bf2f((u16)vn[2]);
        const int lb2 = lb + 8 * k;
#pragma unroll
        for (int j = 0; j < 8; j++) {
          float a = bias;
#pragma unroll
          for (int tt = 0; tt < 7; tt++) a += w14[j + tt] * wreg[tt];
          A[(lb2 + j) * 136 + l] = f2bf(a);
        }
      }
    }
    __syncthreads();  // h^T complete
    // pointwise: MFMA over h^T (in A), hold acc, barrier, write staged out into A
    {
      const u16* pwp = wsu + WSU_PW + (layer << 14) + (m0 + r16) * 128 + quad * 8;
      bf16x8 a[4];
      mm_frags(pwp, a);
      f32x4 c4[4];
#pragma unroll
      for (int ni = 0; ni < 4; ni++) {
        int n = nh * 4 + ni;
        const u16* hb = A + (16 * n + r16) * 136 + quad * 8;
        f32x4 c = {0.f, 0.f, 0.f, 0.f};
        c = mfma16(a[0], *(const bf16x8*)(hb), c);
        c = mfma16(a[1], *(const bf16x8*)(hb + 32), c);
        c = mfma16(a[2], *(const bf16x8*)(hb + 64), c);
        c = mfma16(a[3], *(const bf16x8*)(hb + 96), c);
        c4[ni] = c;
      }
      __syncthreads();  // all h^T reads done before overwrite
#pragma unroll
      for (int ni = 0; ni < 4; ni++) {
        int n = nh * 4 + ni;
        u16* sp = A + (m0 + quad * 4) * 136 + 16 * n + r16;
        sp[0] = f2bf(c4[ni][0]); sp[136] = f2bf(c4[ni][1]);
        sp[272] = f2bf(c4[ni][2]); sp[408] = f2bf(c4[ni][3]);
      }
    }
    __syncthreads();
    // res += relu(staged + bias); LN -> A (Xn)
    {
#pragma unroll
      for (int i = 0; i < 16; i++)
        res[i] += fmaxf(bf2f(A[(obase + i) * 136 + l]) + pw_b[layer * 128 + obase + i], 0.f);
      float mu, inv;
      ln_stats(res, red, t, mu, inv);
      const float* wg = norms_w + layer * 16384;
      const float* bg = norms_b + layer * 16384;
#pragma unroll
      for (int i = 0; i < 16; i++) {
        int o = obase + i;
        A[o * 136 + l] = f2bf((res[i] - mu) * inv * wg[o * 128 + l] + bg[o * 128 + l]);
      }
      __syncthreads();
    }
  }

  // ================= MHA: 4 passes x 1 head, Xn hoisted to registers =========
  bf16x8 xf[4];
  mm_frags(A + (m0 + r16) * 136 + quad * 8, xf);
  __syncthreads();  // Xn reads done; A is now free for QH/KH/PN overlays

  u32 att32[8];
#pragma unroll 1
  for (int hd = 0; hd < 4; hd++) {
    // ---- Q,K,V for head hd (j2 = nh*16 + r16 in 0..31)
    {
      const int j2 = nh * 16 + r16;
      const int jrow = hd * 32 + j2;
      {
        bf16x8 w[4];
        mm_frags(wsu + WSU_WQ + jrow * 128 + quad * 8, w);
        f32x4 c = {0.f, 0.f, 0.f, 0.f};
        c = mfma16(xf[0], w[0], c); c = mfma16(xf[1], w[1], c);
        c = mfma16(xf[2], w[2], c); c = mfma16(xf[3], w[3], c);
        float bb = bq[jrow];
#pragma unroll
        for (int r = 0; r < 4; r++)
          QH[(m0 + quad * 4 + r) * 40 + j2] = f2bf((c[r] + bb) * 0.17677669529663687f);
      }
      {
        bf16x8 w[4];
        mm_frags(wsu + WSU_WK + jrow * 128 + quad * 8, w);
        f32x4 c = {0.f, 0.f, 0.f, 0.f};
        c = mfma16(xf[0], w[0], c); c = mfma16(xf[1], w[1], c);
        c = mfma16(xf[2], w[2], c); c = mfma16(xf[3], w[3], c);
        float bb = bk[jrow];
#pragma unroll
        for (int r = 0; r < 4; r++)
          KH[(m0 + quad * 4 + r) * 40 + j2] = f2bf(c[r] + bb);
      }
      {
        bf16x8 w[4];
        mm_frags(wsu + WSU_WV + jrow * 128 + quad * 8, w);
        f32x4 c = {0.f, 0.f, 0.f, 0.f};
        c = mfma16(xf[0], w[0], c); c = mfma16(xf[1], w[1], c);
        c = mfma16(xf[2], w[2], c); c = mfma16(xf[3], w[3], c);
        float bb = bv[jrow];
        u32 lo = (u32)f2bf(c[0] + bb) | ((u32)f2bf(c[1] + bb) << 16);
        u32 hi = (u32)f2bf(c[2] + bb) | ((u32)f2bf(c[3] + bb) << 16);
        u16* vp = VTb + j2 * 136 + m0 + quad * 4;
        *(u32*)(vp) = lo;
        *(u32*)(vp + 2) = hi;
      }
    }
    __syncthreads();  // B0: QH/KH/VTb visible
    // ---- scores: each dup wave computes ITS 4 key-tiles only (no duplication)
    f32x4 sc[4];
    {
      bf16x8 aq = *(const bf16x8*)(QH + (mq0 + r16) * 40 + quad * 8);
#pragma unroll
      for (int ni = 0; ni < 4; ni++) {
        f32x4 z = {0.f, 0.f, 0.f, 0.f};
        sc[ni] = mfma16(aq, *(const bf16x8*)(KH + ((dup * 4 + ni) * 16 + r16) * 40 + quad * 8), z);
      }
#pragma unroll
      for (int ni = 0; ni < 4; ni++) {
        float mv = mask_s[(dup * 4 + ni) * 16 + r16];
        if (mv > 0.5f) { sc[ni][0] = NEGF; sc[ni][1] = NEGF; sc[ni][2] = NEGF; sc[ni][3] = NEGF; }
      }
    }
    // ---- partial row max, exchange across dup pair via EX
    float mxr[4];
#pragma unroll
    for (int r = 0; r < 4; r++) {
      float mx = fmaxf(fmaxf(sc[0][r], sc[1][r]), fmaxf(sc[2][r], sc[3][r]));
      mx = fmaxf(mx, __shfl_xor(mx, 1, 64));
      mx = fmaxf(mx, __shfl_xor(mx, 2, 64));
      mx = fmaxf(mx, __shfl_xor(mx, 4, 64));
      mx = fmaxf(mx, __shfl_xor(mx, 8, 64));
      if (r16 == 0) EX[dup * 128 + mq0 + quad * 4 + r] = mx;
      mxr[r] = mx;
    }
    __syncthreads();  // B1: QH/KH reads done (PN may overwrite); maxes posted
    // ---- exp with full max -> PN (own col half); partial sums posted
    float ps[4];
#pragma unroll
    for (int r = 0; r < 4; r++) {
      const int row = mq0 + quad * 4 + r;
      float fm = fmaxf(mxr[r], EX[(dup ^ 1) * 128 + row]);
      float s = 0.f;
      u16* pp2 = PN + row * 136 + r16;
#pragma unroll
      for (int ni = 0; ni < 4; ni++) {
        float p = __expf(sc[ni][r] - fm);
        pp2[(dup * 4 + ni) * 16] = f2bf(p);
        s += p;
      }
      s += __shfl_xor(s, 1, 64);
      s += __shfl_xor(s, 2, 64);
      s += __shfl_xor(s, 4, 64);
      s += __shfl_xor(s, 8, 64);
      if (r16 == 0) EX[256 + dup * 128 + row] = s;
      ps[r] = s;
    }
    __syncthreads();  // B2: both PN halves + sums complete
    // ---- PV: dims half = dup
    {
      const u16* pq = PN + (mq0 + r16) * 136 + quad * 8;
      const u16* vb = VTb + (dup * 16 + r16) * 136 + quad * 8;
      f32x4 c = {0.f, 0.f, 0.f, 0.f};
      c = mfma16(*(const bf16x8*)(pq), *(const bf16x8*)(vb), c);
      c = mfma16(*(const bf16x8*)(pq + 32), *(const bf16x8*)(vb + 32), c);
      c = mfma16(*(const bf16x8*)(pq + 64), *(const bf16x8*)(vb + 64), c);
      c = mfma16(*(const bf16x8*)(pq + 96), *(const bf16x8*)(vb + 96), c);
      float v0 = c[0] / (ps[0] + EX[256 + (dup ^ 1) * 128 + mq0 + quad * 4 + 0]);
      float v1 = c[1] / (ps[1] + EX[256 + (dup ^ 1) * 128 + mq0 + quad * 4 + 1]);
      float v2 = c[2] / (ps[2] + EX[256 + (dup ^ 1) * 128 + mq0 + quad * 4 + 2]);
      float v3 = c[3] / (ps[3] + EX[256 + (dup ^ 1) * 128 + mq0 + quad * 4 + 3]);
      att32[hd * 2 + 0] = (u32)f2bf(v0) | ((u32)f2bf(v1) << 16);
      att32[hd * 2 + 1] = (u32)f2bf(v2) | ((u32)f2bf(v3) << 16);
    }
    __syncthreads();  // B3: PN/VTb reads done before next pass overwrites
  }

  // ---- ATT (bf16) -> A
#pragma unroll
  for (int hd = 0; hd < 4; hd++)
#pragma unroll
    for (int i = 0; i < 2; i++)
#pragma unroll
      for (int h = 0; h < 2; h++)
        A[(mq0 + quad * 4 + 2 * i + h) * 136 + hd * 32 + dup * 16 + r16] =
            (u16)(att32[hd * 2 + i] >> (16 * h));
  __syncthreads();  // full ATT rows needed cross-wave
  // ---- Wo: in-place (read ATT, hold acc, barrier, write into A)
  {
    const u16* ap = A + (m0 + r16) * 136 + quad * 8;
    bf16x8 a4[4];
    mm_frags(ap, a4);
    f32x4 c4[4];
#pragma unroll
    for (int ni = 0; ni < 4; ni++) {
      int n = nh * 4 + ni;
      bf16x8 w[4];
      mm_frags(wsu + WSU_WO + (16 * n + r16) * 128 + quad * 8, w);
      f32x4 c = {0.f, 0.f, 0.f, 0.f};
      c = mfma16(a4[0], w[0], c); c = mfma16(a4[1], w[1], c);
      c = mfma16(a4[2], w[2], c); c = mfma16(a4[3], w[3], c);
      c4[ni] = c;
    }
    __syncthreads();  // all ATT reads done
#pragma unroll
    for (int ni = 0; ni < 4; ni++) {
      int n = nh * 4 + ni;
      u16* sp = A + (m0 + quad * 4) * 136 + 16 * n + r16;
      sp[0] = f2bf(c4[ni][0]); sp[136] = f2bf(c4[ni][1]);
      sp[272] = f2bf(c4[ni][2]); sp[408] = f2bf(c4[ni][3]);
    }
  }
  __syncthreads();
  // res += att + bo; final LN -> X^T into A
  {
    float bol = bo[l];
#pragma unroll
    for (int i = 0; i < 16; i++) res[i] += bf2f(A[(obase + i) * 136 + l]) + bol;
    float mu, inv;
    ln_stats(res, red, t, mu, inv);
#pragma unroll
    for (int i = 0; i < 16; i += 2) {
      int o = obase + i;
      float v0 = (res[i] - mu) * inv * norme_w[o * 128 + l] + norme_b[o * 128 + l];
      float v1 = (res[i + 1] - mu) * inv * norme_w[(o + 1) * 128 + l] + norme_b[(o + 1) * 128 + l];
      *(u32*)(A + l * 136 + o) = (u32)f2bf(v0) | ((u32)f2bf(v1) << 16);
    }
    __syncthreads();
  }
  // ---- FC: in-place (read XT, hold acc, barrier, write into A)
  {
    const u16* fp = wsu + WSU_FC + (m0 + r16) * 128 + quad * 8;
    bf16x8 a4[4];
    mm_frags(fp, a4);
    f32x4 c4[4];
#pragma unroll
    for (int ni = 0; ni < 4; ni++) {
      int n = nh * 4 + ni;
      const u16* hb = A + (16 * n + r16) * 136 + quad * 8;
      f32x4 c = {0.f, 0.f, 0.f, 0.f};
      c = mfma16(a4[0], *(const bf16x8*)(hb), c);
      c = mfma16(a4[1], *(const bf16x8*)(hb + 32), c);
      c = mfma16(a4[2], *(const bf16x8*)(hb + 64), c);
      c = mfma16(a4[3], *(const bf16x8*)(hb + 96), c);
      c4[ni] = c;
    }
    __syncthreads();  // all XT reads done
#pragma unroll
    for (int ni = 0; ni < 4; ni++) {
      int n = nh * 4 + ni;
      u16* sp = A + (m0 + quad * 4) * 136 + 16 * n + r16;
      sp[0] = f2bf(c4[ni][0]); sp[136] = f2bf(c4[ni][1]);
      sp[272] = f2bf(c4[ni][2]); sp[408] = f2bf(c4[ni][3]);
    }
  }
  __syncthreads();
  {
    float* outb = out + (size_t)b * 16384;
#pragma unroll
    for (int i = 0; i < 16; i++) {
      float hv = bf2f(A[(obase + i) * 136 + l]) + fc_b[obase + i];
      outb[(obase + i) * 128 + l] = fmaxf(hv, 0.f) + res[i];
    }
  }
}

extern "C" void kernel_launch(void* const* d_in, const int* in_sizes, int n_in,
                              void* d_out, int out_size, void* d_ws, size_t ws_size,
                              hipStream_t stream) {
  const float* x       = (const float*)d_in[0];
  const int*   mask    = (const int*)d_in[1];
  const float* dw_w    = (const float*)d_in[2];
  const float* dw_b    = (const float*)d_in[3];
  const float* pw_w    = (const float*)d_in[4];
  const float* pw_b    = (const float*)d_in[5];
  const float* normb_w = (const float*)d_in[6];
  const float* normb_b = (const float*)d_in[7];
  const float* norms_w = (const float*)d_in[8];
  const float* norms_b = (const float*)d_in[9];
  const float* norme_w = (const float*)d_in[10];
  const float* norme_b = (const float*)d_in[11];
  const float* Wq      = (const float*)d_in[12];
  const float* bq      = (const float*)d_in[13];
  const float* Wk      = (const float*)d_in[14];
  const float* bk      = (const float*)d_in[15];
  const float* Wv      = (const float*)d_in[16];
  const float* bv      = (const float*)d_in[17];
  const float* Wo      = (const float*)d_in[18];
  const float* bo      = (const float*)d_in[19];
  const float* fc_w    = (const float*)d_in[20];
  const float* fc_b    = (const float*)d_in[21];
  float* out = (float*)d_out;
  u16* wsu = (u16*)d_ws;
  const float* pe = (const float*)(wsu + WSU_END);
  int B = in_sizes[0] / 16384;

  prep_kernel<<<dim3(10, 128), dim3(128), 0, stream>>>(pw_w, fc_w, Wo, Wq, Wk, Wv, wsu);
  enc_kernel<<<dim3(B), dim3(1024), 0, stream>>>(
      x, mask, dw_w, dw_b, pw_b, normb_w, normb_b, norms_w, norms_b,
      norme_w, norme_b, bq, bk, bv, bo, fc_b, wsu, pe, out);
}

// Round 5
// 602.341 us; speedup vs baseline: 1.0698x; 1.0698x over previous
//
#include <hip/hip_runtime.h>

#define NEGF -1e30f
#define EPSF 1e-5f

typedef __attribute__((ext_vector_type(8))) short bf16x8;
typedef __attribute__((ext_vector_type(4))) float f32x4;
typedef unsigned short u16;
typedef unsigned int u32;

// ws layout, ushort units
#define WSU_PW 0            // 4 x 128x128 bf16, natural [o][c]
#define WSU_FC 65536        // [o][c]
#define WSU_WO 81920        // [f][j]
#define WSU_WQ 98304        // [j][l]
#define WSU_WK 114688
#define WSU_WV 131072
#define WSU_END 147456      // then PE as float[16384]

__device__ __forceinline__ u16 f2bf(float x) {
  u32 u = __float_as_uint(x);
  u += 0x7fffu + ((u >> 16) & 1u);
  return (u16)(u >> 16);
}
__device__ __forceinline__ float bf2f(u16 u) {
  return __uint_as_float(((u32)u) << 16);
}
__device__ __forceinline__ f32x4 mfma16(bf16x8 a, bf16x8 b, f32x4 c) {
  return __builtin_amdgcn_mfma_f32_16x16x32_bf16(a, b, c, 0, 0, 0);
}
__device__ __forceinline__ void mm_frags(const u16* base, bf16x8* f) {
  f[0] = *(const bf16x8*)(base);
  f[1] = *(const bf16x8*)(base + 32);
  f[2] = *(const bf16x8*)(base + 64);
  f[3] = *(const bf16x8*)(base + 96);
}

__global__ __launch_bounds__(128) void prep_kernel(
    const float* __restrict__ pw_w, const float* __restrict__ fc_w,
    const float* __restrict__ Wo, const float* __restrict__ Wq,
    const float* __restrict__ Wk, const float* __restrict__ Wv,
    u16* __restrict__ wsu) {
  int job = blockIdx.x, r = blockIdx.y, c = threadIdx.x;
  int idx = r * 128 + c;
  if (job < 4)       wsu[WSU_PW + job * 16384 + idx] = f2bf(pw_w[job * 16384 + idx]);
  else if (job == 4) wsu[WSU_FC + idx] = f2bf(fc_w[idx]);
  else if (job == 5) wsu[WSU_WO + idx] = f2bf(Wo[idx]);
  else if (job == 6) wsu[WSU_WQ + idx] = f2bf(Wq[idx]);
  else if (job == 7) wsu[WSU_WK + idx] = f2bf(Wk[idx]);
  else if (job == 8) wsu[WSU_WV + idx] = f2bf(Wv[idx]);
  else {
    float* pe = (float*)(wsu + WSU_END);
    int d = r, pos = c;
    double freq, phase;
    if ((d & 1) == 0) { freq = pow(10000.0, -(double)d / 128.0); phase = 0.0; }
    else { freq = -pow(10000.0, (1.0 - (double)d) / 128.0); phase = 1.5707963267948966; }
    pe[d * 128 + pos] = (float)sin((double)pos * freq + phase);
  }
}

// fused 2-element plane-LN stats: ONE barrier for both elements
__device__ __forceinline__ void ln_stats2(const float* r0, const float* r1,
                                          float* red0, float* red1, int t,
                                          float& mu0, float& inv0,
                                          float& mu1, float& inv1) {
  float s0 = 0.f, q0 = 0.f, s1 = 0.f, q1 = 0.f;
#pragma unroll
  for (int i = 0; i < 16; i++) {
    float a = r0[i], b = r1[i];
    s0 += a; q0 += a * a; s1 += b; q1 += b * b;
  }
#pragma unroll
  for (int off = 32; off > 0; off >>= 1) {
    s0 += __shfl_down(s0, off, 64); q0 += __shfl_down(q0, off, 64);
    s1 += __shfl_down(s1, off, 64); q1 += __shfl_down(q1, off, 64);
  }
  if ((t & 63) == 0) {
    int w = t >> 6;
    red0[w * 2] = s0; red0[w * 2 + 1] = q0;
    red1[w * 2] = s1; red1[w * 2 + 1] = q1;
  }
  __syncthreads();
  float S0 = 0.f, Q0 = 0.f, S1 = 0.f, Q1 = 0.f;
#pragma unroll
  for (int i = 0; i < 16; i++) {
    S0 += red0[2 * i]; Q0 += red0[2 * i + 1];
    S1 += red1[2 * i]; Q1 += red1[2 * i + 1];
  }
  mu0 = S0 * (1.0f / 16384.0f);
  float v0 = Q0 * (1.0f / 16384.0f) - mu0 * mu0; inv0 = rsqrtf(v0 + EPSF);
  mu1 = S1 * (1.0f / 16384.0f);
  float v1 = Q1 * (1.0f / 16384.0f) - mu1 * mu1; inv1 = rsqrtf(v1 + EPSF);
}

// depthwise conv7 for one element: reads A (Xn), writes h^T into XS. No barrier.
__device__ __forceinline__ void dw_conv(const u16* A, u16* XS, const float* wreg,
                                        float bias, int og, int l) {
  const u16* xrow = A + l * 136;
  const int lb = og << 4;
  bf16x8 vz = {0, 0, 0, 0, 0, 0, 0, 0};
  bf16x8 v0 = (lb == 0) ? vz : *(const bf16x8*)(xrow + lb - 8);
  bf16x8 v1 = *(const bf16x8*)(xrow + lb);
  bf16x8 v2 = *(const bf16x8*)(xrow + lb + 8);
  bf16x8 v3 = (lb == 112) ? vz : *(const bf16x8*)(xrow + lb + 16);
#pragma unroll
  for (int k = 0; k < 2; k++) {
    bf16x8 vp = k ? v1 : v0;
    bf16x8 vc = k ? v2 : v1;
    bf16x8 vn = k ? v3 : v2;
    float w14[14];
    w14[0] = bf2f((u16)vp[5]); w14[1] = bf2f((u16)vp[6]); w14[2] = bf2f((u16)vp[7]);
#pragma unroll
    for (int j = 0; j < 8; j++) w14[3 + j] = bf2f((u16)vc[j]);
    w14[11] = bf2f((u16)vn[0]); w14[12] = bf2f((u16)vn[1]); w14[13] = bf2f((u16)vn[2]);
    const int lb2 = lb + 8 * k;
#pragma unroll
    for (int j = 0; j < 8; j++) {
      float a = bias;
#pragma unroll
      for (int tt = 0; tt < 7; tt++) a += w14[j + tt] * wreg[tt];
      XS[(lb2 + j) * 136 + l] = f2bf(a);
    }
  }
}

// staged GEMM, shared A-side (weights), per-element B-side; writes bf16 tiles.
__device__ __forceinline__ void gemm_stage2(const u16* aB, int aS,
                                            const u16* b0B, const u16* b1B, int bS,
                                            u16* d0, u16* d1,
                                            int m0, int nh, int r16, int quad) {
  bf16x8 a[4];
  mm_frags(aB + (m0 + r16) * aS + quad * 8, a);
#pragma unroll
  for (int ni = 0; ni < 4; ni++) {
    int n = nh * 4 + ni;
    {
      bf16x8 w[4];
      mm_frags(b0B + (16 * n + r16) * bS + quad * 8, w);
      f32x4 c = {0.f, 0.f, 0.f, 0.f};
      c = mfma16(a[0], w[0], c); c = mfma16(a[1], w[1], c);
      c = mfma16(a[2], w[2], c); c = mfma16(a[3], w[3], c);
      u16* sp = d0 + (m0 + quad * 4) * 136 + 16 * n + r16;
      sp[0] = f2bf(c[0]); sp[136] = f2bf(c[1]); sp[272] = f2bf(c[2]); sp[408] = f2bf(c[3]);
    }
    {
      bf16x8 w[4];
      mm_frags(b1B + (16 * n + r16) * bS + quad * 8, w);
      f32x4 c = {0.f, 0.f, 0.f, 0.f};
      c = mfma16(a[0], w[0], c); c = mfma16(a[1], w[1], c);
      c = mfma16(a[2], w[2], c); c = mfma16(a[3], w[3], c);
      u16* sp = d1 + (m0 + quad * 4) * 136 + 16 * n + r16;
      sp[0] = f2bf(c[0]); sp[136] = f2bf(c[1]); sp[272] = f2bf(c[2]); sp[408] = f2bf(c[3]);
    }
  }
}

// staged GEMM, shared B-side (weights), per-element A-side.
__device__ __forceinline__ void gemm_stage2b(const u16* a0B, const u16* a1B, int aS,
                                             const u16* bB, int bS,
                                             u16* d0, u16* d1,
                                             int m0, int nh, int r16, int quad) {
  bf16x8 a0[4], a1[4];
  mm_frags(a0B + (m0 + r16) * aS + quad * 8, a0);
  mm_frags(a1B + (m0 + r16) * aS + quad * 8, a1);
#pragma unroll
  for (int ni = 0; ni < 4; ni++) {
    int n = nh * 4 + ni;
    bf16x8 w[4];
    mm_frags(bB + (16 * n + r16) * bS + quad * 8, w);
    {
      f32x4 c = {0.f, 0.f, 0.f, 0.f};
      c = mfma16(a0[0], w[0], c); c = mfma16(a0[1], w[1], c);
      c = mfma16(a0[2], w[2], c); c = mfma16(a0[3], w[3], c);
      u16* sp = d0 + (m0 + quad * 4) * 136 + 16 * n + r16;
      sp[0] = f2bf(c[0]); sp[136] = f2bf(c[1]); sp[272] = f2bf(c[2]); sp[408] = f2bf(c[3]);
    }
    {
      f32x4 c = {0.f, 0.f, 0.f, 0.f};
      c = mfma16(a1[0], w[0], c); c = mfma16(a1[1], w[1], c);
      c = mfma16(a1[2], w[2], c); c = mfma16(a1[3], w[3], c);
      u16* sp = d1 + (m0 + quad * 4) * 136 + 16 * n + r16;
      sp[0] = f2bf(c[0]); sp[136] = f2bf(c[1]); sp[272] = f2bf(c[2]); sp[408] = f2bf(c[3]);
    }
  }
}

// QKV for one head, both elements; weights loaded once.
__device__ __forceinline__ void qkv2(const u16* XS0, const u16* XS1,
                                     u16* QH0, u16* QH1, u16* KH0, u16* KH1,
                                     u16* VT0, u16* VT1,
                                     const u16* wsu, int jrow,
                                     float bqv, float bkv, float bvv,
                                     int m0, int j2, int r16, int quad) {
  bf16x8 x0[4], x1[4];
  mm_frags(XS0 + (m0 + r16) * 136 + quad * 8, x0);
  mm_frags(XS1 + (m0 + r16) * 136 + quad * 8, x1);
  {
    bf16x8 w[4];
    mm_frags(wsu + WSU_WQ + jrow * 128 + quad * 8, w);
    f32x4 c0 = {0.f, 0.f, 0.f, 0.f}, c1 = {0.f, 0.f, 0.f, 0.f};
    c0 = mfma16(x0[0], w[0], c0); c0 = mfma16(x0[1], w[1], c0);
    c0 = mfma16(x0[2], w[2], c0); c0 = mfma16(x0[3], w[3], c0);
    c1 = mfma16(x1[0], w[0], c1); c1 = mfma16(x1[1], w[1], c1);
    c1 = mfma16(x1[2], w[2], c1); c1 = mfma16(x1[3], w[3], c1);
#pragma unroll
    for (int r = 0; r < 4; r++) {
      QH0[(m0 + quad * 4 + r) * 40 + j2] = f2bf((c0[r] + bqv) * 0.17677669529663687f);
      QH1[(m0 + quad * 4 + r) * 40 + j2] = f2bf((c1[r] + bqv) * 0.17677669529663687f);
    }
  }
  {
    bf16x8 w[4];
    mm_frags(wsu + WSU_WK + jrow * 128 + quad * 8, w);
    f32x4 c0 = {0.f, 0.f, 0.f, 0.f}, c1 = {0.f, 0.f, 0.f, 0.f};
    c0 = mfma16(x0[0], w[0], c0); c0 = mfma16(x0[1], w[1], c0);
    c0 = mfma16(x0[2], w[2], c0); c0 = mfma16(x0[3], w[3], c0);
    c1 = mfma16(x1[0], w[0], c1); c1 = mfma16(x1[1], w[1], c1);
    c1 = mfma16(x1[2], w[2], c1); c1 = mfma16(x1[3], w[3], c1);
#pragma unroll
    for (int r = 0; r < 4; r++) {
      KH0[(m0 + quad * 4 + r) * 40 + j2] = f2bf(c0[r] + bkv);
      KH1[(m0 + quad * 4 + r) * 40 + j2] = f2bf(c1[r] + bkv);
    }
  }
  {
    bf16x8 w[4];
    mm_frags(wsu + WSU_WV + jrow * 128 + quad * 8, w);
    f32x4 c0 = {0.f, 0.f, 0.f, 0.f}, c1 = {0.f, 0.f, 0.f, 0.f};
    c0 = mfma16(x0[0], w[0], c0); c0 = mfma16(x0[1], w[1], c0);
    c0 = mfma16(x0[2], w[2], c0); c0 = mfma16(x0[3], w[3], c0);
    c1 = mfma16(x1[0], w[0], c1); c1 = mfma16(x1[1], w[1], c1);
    c1 = mfma16(x1[2], w[2], c1); c1 = mfma16(x1[3], w[3], c1);
    u16* vp0 = VT0 + j2 * 136 + m0 + quad * 4;
    u16* vp1 = VT1 + j2 * 136 + m0 + quad * 4;
    *(u32*)(vp0) = (u32)f2bf(c0[0] + bvv) | ((u32)f2bf(c0[1] + bvv) << 16);
    *(u32*)(vp0 + 2) = (u32)f2bf(c0[2] + bvv) | ((u32)f2bf(c0[3] + bvv) << 16);
    *(u32*)(vp1) = (u32)f2bf(c1[0] + bvv) | ((u32)f2bf(c1[1] + bvv) << 16);
    *(u32*)(vp1 + 2) = (u32)f2bf(c1[2] + bvv) | ((u32)f2bf(c1[3] + bvv) << 16);
  }
}

__device__ __forceinline__ void mha_scores(const u16* QH, const u16* KH, const float* msk,
                                           float* EX, int dup, int mq0, int r16, int quad,
                                           f32x4 (&sc)[4], float (&mxr)[4]) {
  bf16x8 aq = *(const bf16x8*)(QH + (mq0 + r16) * 40 + quad * 8);
#pragma unroll
  for (int ni = 0; ni < 4; ni++) {
    f32x4 z = {0.f, 0.f, 0.f, 0.f};
    sc[ni] = mfma16(aq, *(const bf16x8*)(KH + ((dup * 4 + ni) * 16 + r16) * 40 + quad * 8), z);
  }
#pragma unroll
  for (int ni = 0; ni < 4; ni++) {
    float mv = msk[(dup * 4 + ni) * 16 + r16];
    if (mv > 0.5f) { sc[ni][0] = NEGF; sc[ni][1] = NEGF; sc[ni][2] = NEGF; sc[ni][3] = NEGF; }
  }
#pragma unroll
  for (int r = 0; r < 4; r++) {
    float mx = fmaxf(fmaxf(sc[0][r], sc[1][r]), fmaxf(sc[2][r], sc[3][r]));
    mx = fmaxf(mx, __shfl_xor(mx, 1, 64));
    mx = fmaxf(mx, __shfl_xor(mx, 2, 64));
    mx = fmaxf(mx, __shfl_xor(mx, 4, 64));
    mx = fmaxf(mx, __shfl_xor(mx, 8, 64));
    if (r16 == 0) EX[dup * 128 + mq0 + quad * 4 + r] = mx;
    mxr[r] = mx;
  }
}

__device__ __forceinline__ void mha_exp(u16* PN, float* EX, const f32x4 (&sc)[4],
                                        const float (&mxr)[4], int dup, int mq0,
                                        int r16, int quad, float (&ps)[4]) {
#pragma unroll
  for (int r = 0; r < 4; r++) {
    const int row = mq0 + quad * 4 + r;
    float fm = fmaxf(mxr[r], EX[(dup ^ 1) * 128 + row]);
    float s = 0.f;
    u16* pp = PN + row * 136 + r16;
#pragma unroll
    for (int ni = 0; ni < 4; ni++) {
      float p = __expf(sc[ni][r] - fm);
      pp[(dup * 4 + ni) * 16] = f2bf(p);
      s += p;
    }
    s += __shfl_xor(s, 1, 64);
    s += __shfl_xor(s, 2, 64);
    s += __shfl_xor(s, 4, 64);
    s += __shfl_xor(s, 8, 64);
    if (r16 == 0) EX[256 + dup * 128 + row] = s;
    ps[r] = s;
  }
}

__device__ __forceinline__ void mha_pv(const u16* PN, const u16* VT, const float* EX,
                                       const float (&ps)[4], int dup, int mq0,
                                       int r16, int quad, u32& alo, u32& ahi) {
  const u16* pq = PN + (mq0 + r16) * 136 + quad * 8;
  const u16* vb = VT + (dup * 16 + r16) * 136 + quad * 8;
  f32x4 c = {0.f, 0.f, 0.f, 0.f};
  c = mfma16(*(const bf16x8*)(pq), *(const bf16x8*)(vb), c);
  c = mfma16(*(const bf16x8*)(pq + 32), *(const bf16x8*)(vb + 32), c);
  c = mfma16(*(const bf16x8*)(pq + 64), *(const bf16x8*)(vb + 64), c);
  c = mfma16(*(const bf16x8*)(pq + 96), *(const bf16x8*)(vb + 96), c);
  float v0 = c[0] / (ps[0] + EX[256 + (dup ^ 1) * 128 + mq0 + quad * 4 + 0]);
  float v1 = c[1] / (ps[1] + EX[256 + (dup ^ 1) * 128 + mq0 + quad * 4 + 1]);
  float v2 = c[2] / (ps[2] + EX[256 + (dup ^ 1) * 128 + mq0 + quad * 4 + 2]);
  float v3 = c[3] / (ps[3] + EX[256 + (dup ^ 1) * 128 + mq0 + quad * 4 + 3]);
  alo = (u32)f2bf(v0) | ((u32)f2bf(v1) << 16);
  ahi = (u32)f2bf(v2) | ((u32)f2bf(v3) << 16);
}

// 2 batch elements per block. LDS total:
//   2 x (A_raw 34,848 + XS 34,816 + VT 8,704 + EX 2,048) + mask 1,024 + red 256
// = 162,112 B <= 163,840. Occupancy stays 1 block/CU (proven cap) — the win is
// ILP: every barrier segment carries both elements' work, halving stall share,
// and all weights are fetched once per 2 elements.
__global__ __launch_bounds__(1024) void enc_kernel(
    const float* __restrict__ x, const int* __restrict__ mask,
    const float* __restrict__ dw_w, const float* __restrict__ dw_b,
    const float* __restrict__ pw_b,
    const float* __restrict__ normb_w, const float* __restrict__ normb_b,
    const float* __restrict__ norms_w, const float* __restrict__ norms_b,
    const float* __restrict__ norme_w, const float* __restrict__ norme_b,
    const float* __restrict__ bq, const float* __restrict__ bk,
    const float* __restrict__ bv, const float* __restrict__ bo,
    const float* __restrict__ fc_b, const u16* __restrict__ wsu,
    const float* __restrict__ pe, float* __restrict__ out, int B) {
  __shared__ __align__(16) u16 A0_raw[128 * 136 + 16];
  __shared__ __align__(16) u16 A1_raw[128 * 136 + 16];
  __shared__ __align__(16) u16 XS0[128 * 136];
  __shared__ __align__(16) u16 XS1[128 * 136];
  __shared__ __align__(16) u16 VT0[32 * 136];
  __shared__ __align__(16) u16 VT1[32 * 136];
  __shared__ float EX0[512], EX1[512];
  __shared__ float msk0[128], msk1[128];
  __shared__ float red0[32], red1[32];
  u16* A0 = A0_raw + 8;
  u16* A1 = A1_raw + 8;
  // MHA overlays (Xn parked in XS during MHA):
  u16* QH0 = A0; u16* KH0 = A0 + 5120; u16* PN0 = A0;
  u16* QH1 = A1; u16* KH1 = A1 + 5120; u16* PN1 = A1;

  const int t = threadIdx.x;
  const int b0 = 2 * blockIdx.x;
  const int b1 = b0 + 1;
  const bool has1 = (b1 < B);
  const int lane = t & 63;
  const int r16 = lane & 15;
  const int quad = lane >> 4;
  const int wv = t >> 6;
  const int m0 = __builtin_amdgcn_readfirstlane((wv >> 1) << 4);
  const int nh = __builtin_amdgcn_readfirstlane(wv & 1);
  const int l = t & 127;
  const int og = __builtin_amdgcn_readfirstlane(t >> 7);
  const int obase = og << 4;
  const int dup = __builtin_amdgcn_readfirstlane(wv >> 3);
  const int mq0 = __builtin_amdgcn_readfirstlane((wv & 7) << 4);

  if (t < 128) {
    msk0[t] = (float)mask[b0 * 128 + t];
    msk1[t] = has1 ? (float)mask[b1 * 128 + t] : 0.f;
  }

  float res0[16], res1[16];
  {
    const float* xb0 = x + (size_t)b0 * 16384;
    const float* xb1 = x + (size_t)b1 * 16384;
#pragma unroll
    for (int i = 0; i < 16; i++) {
      int o = obase + i;
      float p = pe[o * 128 + l];
      res0[i] = xb0[o * 128 + l] + p;
      res1[i] = has1 ? (xb1[o * 128 + l] + p) : 0.f;
    }
  }
  {
    float mu0, inv0, mu1, inv1;
    ln_stats2(res0, res1, red0, red1, t, mu0, inv0, mu1, inv1);
#pragma unroll
    for (int i = 0; i < 16; i++) {
      int o = obase + i;
      float w_ = normb_w[o * 128 + l], bb = normb_b[o * 128 + l];
      A0[o * 136 + l] = f2bf((res0[i] - mu0) * inv0 * w_ + bb);
      A1[o * 136 + l] = f2bf((res1[i] - mu1) * inv1 * w_ + bb);
    }
    __syncthreads();
  }

  // ================= 4x separable conv blocks =================
#pragma unroll 1
  for (int layer = 0; layer < 4; layer++) {
    {
      const float* dwp = dw_w + layer * 896 + l * 7;
      float wreg[7];
#pragma unroll
      for (int j = 0; j < 7; j++) wreg[j] = dwp[j];
      float bias = dw_b[layer * 128 + l];
      dw_conv(A0, XS0, wreg, bias, og, l);
      dw_conv(A1, XS1, wreg, bias, og, l);
    }
    __syncthreads();  // h^T complete
    gemm_stage2(wsu + WSU_PW + (layer << 14), 128, XS0, XS1, 136, A0, A1,
                m0, nh, r16, quad);
    __syncthreads();  // PW-out staged in A
    {
      u16* t0 = (layer == 3) ? XS0 : A0;
      u16* t1 = (layer == 3) ? XS1 : A1;
#pragma unroll
      for (int i = 0; i < 16; i++) {
        float pb = pw_b[layer * 128 + obase + i];
        res0[i] += fmaxf(bf2f(A0[(obase + i) * 136 + l]) + pb, 0.f);
        res1[i] += fmaxf(bf2f(A1[(obase + i) * 136 + l]) + pb, 0.f);
      }
      float mu0, inv0, mu1, inv1;
      ln_stats2(res0, res1, red0, red1, t, mu0, inv0, mu1, inv1);
      const float* wg = norms_w + layer * 16384;
      const float* bg = norms_b + layer * 16384;
#pragma unroll
      for (int i = 0; i < 16; i++) {
        int o = obase + i;
        float w_ = wg[o * 128 + l], bb = bg[o * 128 + l];
        t0[o * 136 + l] = f2bf((res0[i] - mu0) * inv0 * w_ + bb);
        t1[o * 136 + l] = f2bf((res1[i] - mu1) * inv1 * w_ + bb);
      }
      __syncthreads();
    }
  }
  // Xn for MHA now lives in XS0/XS1; A planes free for QH/KH/PN overlays.

  // ================= MHA: 4 heads, both elements per pass =================
  u32 at0lo[4], at0hi[4], at1lo[4], at1hi[4];
#pragma unroll
  for (int hd = 0; hd < 4; hd++) {
    {
      const int j2 = nh * 16 + r16;
      const int jrow = hd * 32 + j2;
      qkv2(XS0, XS1, QH0, QH1, KH0, KH1, VT0, VT1, wsu, jrow,
           bq[jrow], bk[jrow], bv[jrow], m0, j2, r16, quad);
    }
    __syncthreads();  // B0: QH/KH/VT visible
    f32x4 sc0[4], sc1[4];
    float mx0[4], mx1[4];
    mha_scores(QH0, KH0, msk0, EX0, dup, mq0, r16, quad, sc0, mx0);
    mha_scores(QH1, KH1, msk1, EX1, dup, mq0, r16, quad, sc1, mx1);
    __syncthreads();  // B1: QH/KH reads done; maxes posted
    float ps0[4], ps1[4];
    mha_exp(PN0, EX0, sc0, mx0, dup, mq0, r16, quad, ps0);
    mha_exp(PN1, EX1, sc1, mx1, dup, mq0, r16, quad, ps1);
    __syncthreads();  // B2: PN halves + sums complete
    mha_pv(PN0, VT0, EX0, ps0, dup, mq0, r16, quad, at0lo[hd], at0hi[hd]);
    mha_pv(PN1, VT1, EX1, ps1, dup, mq0, r16, quad, at1lo[hd], at1hi[hd]);
    __syncthreads();  // B3: PN/VT reads done before next pass
  }

  // ---- ATT (bf16) -> A planes
#pragma unroll
  for (int hd = 0; hd < 4; hd++) {
    int col = hd * 32 + dup * 16 + r16;
    A0[(mq0 + quad * 4 + 0) * 136 + col] = (u16)(at0lo[hd]);
    A0[(mq0 + quad * 4 + 1) * 136 + col] = (u16)(at0lo[hd] >> 16);
    A0[(mq0 + quad * 4 + 2) * 136 + col] = (u16)(at0hi[hd]);
    A0[(mq0 + quad * 4 + 3) * 136 + col] = (u16)(at0hi[hd] >> 16);
    A1[(mq0 + quad * 4 + 0) * 136 + col] = (u16)(at1lo[hd]);
    A1[(mq0 + quad * 4 + 1) * 136 + col] = (u16)(at1lo[hd] >> 16);
    A1[(mq0 + quad * 4 + 2) * 136 + col] = (u16)(at1hi[hd]);
    A1[(mq0 + quad * 4 + 3) * 136 + col] = (u16)(at1hi[hd] >> 16);
  }
  __syncthreads();
  // ---- Wo: ATT (A) x Wo (shared) -> XS
  gemm_stage2b(A0, A1, 136, wsu + WSU_WO, 128, XS0, XS1, m0, nh, r16, quad);
  __syncthreads();
  // ---- res += att + bo; final LN -> X^T into A
  {
    float bol = bo[l];
#pragma unroll
    for (int i = 0; i < 16; i++) {
      res0[i] += bf2f(XS0[(obase + i) * 136 + l]) + bol;
      res1[i] += bf2f(XS1[(obase + i) * 136 + l]) + bol;
    }
    float mu0, inv0, mu1, inv1;
    ln_stats2(res0, res1, red0, red1, t, mu0, inv0, mu1, inv1);
#pragma unroll
    for (int i = 0; i < 16; i += 2) {
      int o = obase + i;
      float wa = norme_w[o * 128 + l], ba = norme_b[o * 128 + l];
      float wb = norme_w[(o + 1) * 128 + l], bb = norme_b[(o + 1) * 128 + l];
      float u0 = (res0[i] - mu0) * inv0 * wa + ba;
      float u1 = (res0[i + 1] - mu0) * inv0 * wb + bb;
      *(u32*)(A0 + l * 136 + o) = (u32)f2bf(u0) | ((u32)f2bf(u1) << 16);
      float v0 = (res1[i] - mu1) * inv1 * wa + ba;
      float v1 = (res1[i + 1] - mu1) * inv1 * wb + bb;
      *(u32*)(A1 + l * 136 + o) = (u32)f2bf(v0) | ((u32)f2bf(v1) << 16);
    }
    __syncthreads();
  }
  // ---- FC: fc (shared) x XT (A) -> XS
  gemm_stage2(wsu + WSU_FC, 128, A0, A1, 136, XS0, XS1, m0, nh, r16, quad);
  __syncthreads();
  {
    float* ob0 = out + (size_t)b0 * 16384;
    float* ob1 = out + (size_t)b1 * 16384;
#pragma unroll
    for (int i = 0; i < 16; i++) {
      int o = obase + i;
      float fb = fc_b[o];
      float h0 = bf2f(XS0[o * 136 + l]) + fb;
      ob0[o * 128 + l] = fmaxf(h0, 0.f) + res0[i];
      if (has1) {
        float h1 = bf2f(XS1[o * 136 + l]) + fb;
        ob1[o * 128 + l] = fmaxf(h1, 0.f) + res1[i];
      }
    }
  }
}

extern "C" void kernel_launch(void* const* d_in, const int* in_sizes, int n_in,
                              void* d_out, int out_size, void* d_ws, size_t ws_size,
                              hipStream_t stream) {
  const float* x       = (const float*)d_in[0];
  const int*   mask    = (const int*)d_in[1];
  const float* dw_w    = (const float*)d_in[2];
  const float* dw_b    = (const float*)d_in[3];
  const float* pw_w    = (const float*)d_in[4];
  const float* pw_b    = (const float*)d_in[5];
  const float* normb_w = (const float*)d_in[6];
  const float* normb_b = (const float*)d_in[7];
  const float* norms_w = (const float*)d_in[8];
  const float* norms_b = (const float*)d_in[9];
  const float* norme_w = (const float*)d_in[10];
  const float* norme_b = (const float*)d_in[11];
  const float* Wq      = (const float*)d_in[12];
  const float* bq      = (const float*)d_in[13];
  const float* Wk      = (const float*)d_in[14];
  const float* bk      = (const float*)d_in[15];
  const float* Wv      = (const float*)d_in[16];
  const float* bv      = (const float*)d_in[17];
  const float* Wo      = (const float*)d_in[18];
  const float* bo      = (const float*)d_in[19];
  const float* fc_w    = (const float*)d_in[20];
  const float* fc_b    = (const float*)d_in[21];
  float* out = (float*)d_out;
  u16* wsu = (u16*)d_ws;
  const float* pe = (const float*)(wsu + WSU_END);
  int B = in_sizes[0] / 16384;

  prep_kernel<<<dim3(10, 128), dim3(128), 0, stream>>>(pw_w, fc_w, Wo, Wq, Wk, Wv, wsu);
  enc_kernel<<<dim3((B + 1) / 2), dim3(1024), 0, stream>>>(
      x, mask, dw_w, dw_b, pw_b, normb_w, normb_b, norms_w, norms_b,
      norme_w, norme_b, bq, bk, bv, bo, fc_b, wsu, pe, out, B);
}